// Round 2
// baseline (963.929 us; speedup 1.0000x reference)
//
#include <hip/hip_runtime.h>

#define B_      32
#define S_      64
#define E_      512
#define V_      50257
#define NPAD_   50304      // 393*128
#define M_      2048       // B*S
#define NMASK_  524288.0   // B * 32 * E
#define EPS_    0.4f

typedef _Float16 half8 __attribute__((ext_vector_type(8)));
typedef float f32x4 __attribute__((ext_vector_type(4)));

__device__ __forceinline__ float wave_sum(float s) {
#pragma unroll
    for (int d = 32; d; d >>= 1) s += __shfl_xor(s, d);
    return s;
}

// ---------------- K1: abs_grad[m] = sum_e |grad[m,e]| -----------------------
__global__ void k_absgrad(const float* __restrict__ grad, float* __restrict__ absg) {
    const int row = blockIdx.x * 4 + (threadIdx.x >> 6);
    const int ln  = threadIdx.x & 63;
    const float4* g = (const float4*)(grad + (size_t)row * E_) + ln * 2;
    float4 a = g[0], b = g[1];
    float s = fabsf(a.x) + fabsf(a.y) + fabsf(a.z) + fabsf(a.w)
            + fabsf(b.x) + fabsf(b.y) + fabsf(b.z) + fabsf(b.w);
    s = wave_sum(s);
    if (ln == 0) absg[row] = s;
}

// ---------------- K2: top-32 mask per batch (stable ties, lower idx first) --
__global__ void k_topk(const float* __restrict__ absg, int* __restrict__ mask) {
    __shared__ float sh[S_];
    const int b = blockIdx.x, s = threadIdx.x;
    const float v = absg[b * S_ + s];
    sh[s] = v;
    __syncthreads();
    int rank = 0;
#pragma unroll
    for (int t = 0; t < S_; ++t) {
        float o = sh[t];
        rank += (o > v) || (o == v && t < s);
    }
    mask[b * S_ + s] = (rank < 32);
}

// ---------------- K3: masked sum / sumsq partials ---------------------------
__global__ void k_stats1(const float* __restrict__ grad, const int* __restrict__ mask,
                         float* __restrict__ part) {
    const int tid = threadIdx.x;
    float s1 = 0.f, s2 = 0.f;
    for (int i = blockIdx.x * 256 + tid; i < M_ * E_; i += 128 * 256) {
        if (mask[i >> 9]) {
            float x = grad[i];
            s1 += x; s2 += x * x;
        }
    }
    s1 = wave_sum(s1); s2 = wave_sum(s2);
    __shared__ float r1[4], r2[4];
    if ((tid & 63) == 0) { r1[tid >> 6] = s1; r2[tid >> 6] = s2; }
    __syncthreads();
    if (tid == 0) {
        part[2 * blockIdx.x]     = r1[0] + r1[1] + r1[2] + r1[3];
        part[2 * blockIdx.x + 1] = r2[0] + r2[1] + r2[2] + r2[3];
    }
}

// ---------------- K4: finalize mean/std -> lb, ub ---------------------------
__global__ void k_stats2(const float* __restrict__ part, float* __restrict__ stats) {
    if (threadIdx.x == 0) {
        double s1 = 0.0, s2 = 0.0;
        for (int i = 0; i < 128; ++i) { s1 += part[2 * i]; s2 += part[2 * i + 1]; }
        const double n = NMASK_;
        double mean = s1 / n;
        double var  = (s2 - s1 * s1 / n) / (n - 1.0);
        double sd   = sqrt(var);
        stats[0] = (float)(mean - 3.0 * sd);   // lb
        stats[1] = (float)(mean + 3.0 * sd);   // ub
    }
}

// ---------------- K5: perturbed (f16) + 1/p_norm ----------------------------
__global__ void k_pert(const float* __restrict__ grad, const float* __restrict__ emb,
                       const int* __restrict__ utt, const int* __restrict__ mask,
                       const float* __restrict__ stats,
                       _Float16* __restrict__ pf16, float* __restrict__ inv_p) {
    const int row = blockIdx.x * 4 + (threadIdx.x >> 6);
    const int ln  = threadIdx.x & 63;
    const int tok = utt[row];
    const int msk = mask[row];
    const float lb = stats[0], ub = stats[1];
    const float* gp = grad + (size_t)row * E_ + ln * 8;
    const float* ep = emb + (size_t)tok * E_ + ln * 8;
    float4 g0 = *(const float4*)gp, g1 = *(const float4*)(gp + 4);
    float4 e0 = *(const float4*)ep, e1 = *(const float4*)(ep + 4);
    float gx[8] = {g0.x, g0.y, g0.z, g0.w, g1.x, g1.y, g1.z, g1.w};
    float ex[8] = {e0.x, e0.y, e0.z, e0.w, e1.x, e1.y, e1.z, e1.w};
    half8 h;
    float ss = 0.f;
#pragma unroll
    for (int i = 0; i < 8; ++i) {
        float x = gx[i];
        float val = ex[i];
        if (msk && (x < lb || x > ub)) val += (x > 0.f) ? EPS_ : -EPS_;
        ss += val * val;
        h[i] = (_Float16)val;
    }
    *(half8*)(pf16 + (size_t)row * E_ + ln * 8) = h;
    ss = wave_sum(ss);
    if (ln == 0) inv_p[row] = 1.f / fmaxf(sqrtf(ss), 1e-8f);
}

// ---------------- K6: emb -> f16 (zero-padded) + 1/t_norm -------------------
__global__ void k_emb(const float* __restrict__ emb, _Float16* __restrict__ ef16,
                      float* __restrict__ inv_t) {
    const int row = blockIdx.x * 4 + (threadIdx.x >> 6);
    const int ln  = threadIdx.x & 63;
    half8 h;
    float ss = 0.f;
    if (row < V_) {
        const float* ep = emb + (size_t)row * E_ + ln * 8;
        float4 e0 = *(const float4*)ep, e1 = *(const float4*)(ep + 4);
        float ex[8] = {e0.x, e0.y, e0.z, e0.w, e1.x, e1.y, e1.z, e1.w};
#pragma unroll
        for (int i = 0; i < 8; ++i) { ss += ex[i] * ex[i]; h[i] = (_Float16)ex[i]; }
    } else {
#pragma unroll
        for (int i = 0; i < 8; ++i) h[i] = (_Float16)0.f;
    }
    *(half8*)(ef16 + (size_t)row * E_ + ln * 8) = h;
    ss = wave_sum(ss);
    if (ln == 0) inv_t[row] = (row < V_) ? 1.f / fmaxf(sqrtf(ss), 1e-8f) : 0.f;
}

// ---------------- K7: GEMM + normalize + store + argmax ---------------------
__device__ __forceinline__ void glds16(const _Float16* g, void* l) {
    __builtin_amdgcn_global_load_lds(
        (const __attribute__((address_space(1))) void*)g,
        (__attribute__((address_space(3))) void*)l, 16, 0, 0);
}

__global__ __launch_bounds__(256) void k_gemm(
    const _Float16* __restrict__ A,    // [M_][E_] perturbed f16
    const _Float16* __restrict__ Bm,   // [NPAD_][E_] emb f16
    const float* __restrict__ inv_p,   // [M_]
    const float* __restrict__ inv_t,   // [NPAD_]
    float* __restrict__ simout,        // [M_][V_]
    unsigned long long* __restrict__ keys) {
    __shared__ _Float16 As[128][32];
    __shared__ _Float16 Bs[128][32];
    const int tid = threadIdx.x;
    const int wv = tid >> 6, ln = tid & 63;
    const int m0 = blockIdx.y * 128, n0 = blockIdx.x * 128;
    const int wr = wv >> 1, wc = wv & 1;
    const int lr = ln & 15, lk = (ln >> 4) * 8;

    f32x4 acc[4][4];
#pragma unroll
    for (int i = 0; i < 4; ++i)
#pragma unroll
        for (int j = 0; j < 4; ++j) acc[i][j] = (f32x4){0.f, 0.f, 0.f, 0.f};

    // staging map: thread t loads 16B; tile row = it*64 + wv*16 + (ln>>2), col = (ln&3)*8
    const int srow = wv * 16 + (ln >> 2);
    const int scol = (ln & 3) * 8;
    const _Float16* gA = A  + (size_t)(m0 + srow) * E_ + scol;
    const _Float16* gB = Bm + (size_t)(n0 + srow) * E_ + scol;
    char* lA = (char*)&As[0][0] + wv * 1024;   // HW adds lane*16
    char* lB = (char*)&Bs[0][0] + wv * 1024;

    for (int k0 = 0; k0 < E_; k0 += 32) {
        glds16(gA + k0,            lA);
        glds16(gA + 64 * E_ + k0,  lA + 4096);
        glds16(gB + k0,            lB);
        glds16(gB + 64 * E_ + k0,  lB + 4096);
        __syncthreads();
        half8 af[4], bf[4];
#pragma unroll
        for (int f = 0; f < 4; ++f) {
            af[f] = *(const half8*)&As[wr * 64 + f * 16 + lr][lk];
            bf[f] = *(const half8*)&Bs[wc * 64 + f * 16 + lr][lk];
        }
#pragma unroll
        for (int i = 0; i < 4; ++i)
#pragma unroll
            for (int j = 0; j < 4; ++j)
                acc[i][j] = __builtin_amdgcn_mfma_f32_16x16x32_f16(af[i], bf[j], acc[i][j], 0, 0, 0);
        __syncthreads();
    }

    // epilogue: C/D layout col = lane&15, row = (lane>>4)*4 + reg
    int vv[4];
    float itv[4];
#pragma unroll
    for (int fn = 0; fn < 4; ++fn) {
        vv[fn] = n0 + wc * 64 + fn * 16 + lr;
        itv[fn] = inv_t[vv[fn]];
    }
#pragma unroll
    for (int fm = 0; fm < 4; ++fm) {
#pragma unroll
        for (int j = 0; j < 4; ++j) {
            const int m = m0 + wr * 64 + fm * 16 + (ln >> 4) * 4 + j;
            const float ip = inv_p[m];
            float* orow = simout + (size_t)m * V_;
            unsigned long long best = 0ull;
#pragma unroll
            for (int fn = 0; fn < 4; ++fn) {
                const int v = vv[fn];
                if (v < V_) {
                    const float sv = acc[fm][fn][j] * ip * itv[fn];
                    orow[v] = sv;
                    unsigned u = __float_as_uint(sv);
                    u = (u & 0x80000000u) ? ~u : (u | 0x80000000u);
                    unsigned long long e = ((unsigned long long)u << 32) | (unsigned)(~v);
                    best = e > best ? e : best;
                }
            }
#pragma unroll
            for (int d = 1; d < 16; d <<= 1) {
                unsigned long long o = __shfl_xor(best, d);
                best = o > best ? o : best;
            }
            if (lr == 0) atomicMax(keys + m, best);
        }
    }
}

// ---------------- K8: decode argmax keys -> float indices -------------------
__global__ void k_idx(const unsigned long long* __restrict__ keys, float* __restrict__ out) {
    const int i = blockIdx.x * 256 + threadIdx.x;
    if (i < M_) {
        unsigned v = ~(unsigned)(keys[i] & 0xFFFFFFFFull);
        out[i] = (float)v;
    }
}

extern "C" void kernel_launch(void* const* d_in, const int* in_sizes, int n_in,
                              void* d_out, int out_size, void* d_ws, size_t ws_size,
                              hipStream_t stream) {
    const int*   utt  = (const int*)d_in[0];
    const float* emb  = (const float*)d_in[1];
    const float* grad = (const float*)d_in[2];

    char* ws = (char*)d_ws;
    _Float16* embF16  = (_Float16*)(ws);                    // 50304*512*2 = 51,511,296
    _Float16* pertF16 = (_Float16*)(ws + 51511296);         // 2048*512*2  =  2,097,152
    float* inv_t = (float*)(ws + 53608448);                 // 50304*4
    float* inv_p = (float*)(ws + 53809664);                 // 2048*4
    float* absg  = (float*)(ws + 53817856);                 // 2048*4
    int*   mask  = (int*)  (ws + 53826048);                 // 2048*4
    float* part  = (float*)(ws + 53834240);                 // 128*2*4
    float* stats = (float*)(ws + 53835264);                 // 2 floats
    unsigned long long* keys = (unsigned long long*)(ws + 53835520); // 2048*8

    float* outIdx = (float*)d_out;          // nn_idx as float32 [2048]
    float* simout = (float*)d_out + M_;     // sim [2048][50257]

    hipMemsetAsync(keys, 0, M_ * 8, stream);
    k_absgrad<<<M_ / 4, 256, 0, stream>>>(grad, absg);
    k_topk<<<B_, S_, 0, stream>>>(absg, mask);
    k_stats1<<<128, 256, 0, stream>>>(grad, mask, part);
    k_stats2<<<1, 64, 0, stream>>>(part, stats);
    k_pert<<<M_ / 4, 256, 0, stream>>>(grad, emb, utt, mask, stats, pertF16, inv_p);
    k_emb<<<NPAD_ / 4, 256, 0, stream>>>(emb, embF16, inv_t);
    k_gemm<<<dim3(NPAD_ / 128, M_ / 128), 256, 0, stream>>>(pertF16, embF16, inv_p, inv_t, simout, keys);
    k_idx<<<8, 256, 0, stream>>>(keys, outIdx);
}

// Round 3
// 783.778 us; speedup vs baseline: 1.2298x; 1.2298x over previous
//
#include <hip/hip_runtime.h>

#define B_      32
#define S_      64
#define E_      512
#define V_      50257
#define NPAD_   50304      // 393*128
#define M_      2048       // B*S
#define NMASK_  524288.0   // B * 32 * E
#define EPS_    0.4f
#define NWG_    6288       // 16 * 393
#define CPX_    786        // NWG_/8 (exact)

typedef _Float16 half8 __attribute__((ext_vector_type(8)));
typedef float f32x4 __attribute__((ext_vector_type(4)));

__device__ __forceinline__ float wave_sum(float s) {
#pragma unroll
    for (int d = 32; d; d >>= 1) s += __shfl_xor(s, d);
    return s;
}

// ---------------- K1: abs_grad[m] = sum_e |grad[m,e]| -----------------------
__global__ void k_absgrad(const float* __restrict__ grad, float* __restrict__ absg) {
    const int row = blockIdx.x * 4 + (threadIdx.x >> 6);
    const int ln  = threadIdx.x & 63;
    const float4* g = (const float4*)(grad + (size_t)row * E_) + ln * 2;
    float4 a = g[0], b = g[1];
    float s = fabsf(a.x) + fabsf(a.y) + fabsf(a.z) + fabsf(a.w)
            + fabsf(b.x) + fabsf(b.y) + fabsf(b.z) + fabsf(b.w);
    s = wave_sum(s);
    if (ln == 0) absg[row] = s;
}

// ---------------- K2: top-32 mask per batch (stable ties, lower idx first) --
__global__ void k_topk(const float* __restrict__ absg, int* __restrict__ mask) {
    __shared__ float sh[S_];
    const int b = blockIdx.x, s = threadIdx.x;
    const float v = absg[b * S_ + s];
    sh[s] = v;
    __syncthreads();
    int rank = 0;
#pragma unroll
    for (int t = 0; t < S_; ++t) {
        float o = sh[t];
        rank += (o > v) || (o == v && t < s);
    }
    mask[b * S_ + s] = (rank < 32);
}

// ---------------- K3: masked sum / sumsq partials ---------------------------
__global__ void k_stats1(const float* __restrict__ grad, const int* __restrict__ mask,
                         float* __restrict__ part) {
    const int tid = threadIdx.x;
    float s1 = 0.f, s2 = 0.f;
    for (int i = blockIdx.x * 256 + tid; i < M_ * E_; i += 128 * 256) {
        if (mask[i >> 9]) {
            float x = grad[i];
            s1 += x; s2 += x * x;
        }
    }
    s1 = wave_sum(s1); s2 = wave_sum(s2);
    __shared__ float r1[4], r2[4];
    if ((tid & 63) == 0) { r1[tid >> 6] = s1; r2[tid >> 6] = s2; }
    __syncthreads();
    if (tid == 0) {
        part[2 * blockIdx.x]     = r1[0] + r1[1] + r1[2] + r1[3];
        part[2 * blockIdx.x + 1] = r2[0] + r2[1] + r2[2] + r2[3];
    }
}

// ---------------- K4: finalize mean/std -> lb, ub ---------------------------
__global__ void k_stats2(const float* __restrict__ part, float* __restrict__ stats) {
    const int ln = threadIdx.x & 63;
    double s1 = 0.0, s2 = 0.0;
    if (ln < 32) { s1 = part[2 * ln]; s2 = part[2 * ln + 1]; }
    if (ln + 64 < 128) { }  // 128 partial pairs, 64 lanes -> 2 each
    s1 += (double)part[2 * (ln + 64)];
    s2 += (double)part[2 * (ln + 64) + 1];
    if (ln >= 32) { s1 += (double)part[2 * ln]; s2 += (double)part[2 * ln + 1]; }
#pragma unroll
    for (int d = 32; d; d >>= 1) {
        s1 += __shfl_xor(s1, d);
        s2 += __shfl_xor(s2, d);
    }
    if (ln == 0) {
        const double n = NMASK_;
        double mean = s1 / n;
        double var  = (s2 - s1 * s1 / n) / (n - 1.0);
        double sd   = sqrt(var);
        stats[0] = (float)(mean - 3.0 * sd);   // lb
        stats[1] = (float)(mean + 3.0 * sd);   // ub
    }
}

// ---------------- K5: perturbed (f16) + 1/p_norm ----------------------------
__global__ void k_pert(const float* __restrict__ grad, const float* __restrict__ emb,
                       const int* __restrict__ utt, const int* __restrict__ mask,
                       const float* __restrict__ stats,
                       _Float16* __restrict__ pf16, float* __restrict__ inv_p) {
    const int row = blockIdx.x * 4 + (threadIdx.x >> 6);
    const int ln  = threadIdx.x & 63;
    const int tok = utt[row];
    const int msk = mask[row];
    const float lb = stats[0], ub = stats[1];
    const float* gp = grad + (size_t)row * E_ + ln * 8;
    const float* ep = emb + (size_t)tok * E_ + ln * 8;
    float4 g0 = *(const float4*)gp, g1 = *(const float4*)(gp + 4);
    float4 e0 = *(const float4*)ep, e1 = *(const float4*)(ep + 4);
    float gx[8] = {g0.x, g0.y, g0.z, g0.w, g1.x, g1.y, g1.z, g1.w};
    float ex[8] = {e0.x, e0.y, e0.z, e0.w, e1.x, e1.y, e1.z, e1.w};
    half8 h;
    float ss = 0.f;
#pragma unroll
    for (int i = 0; i < 8; ++i) {
        float x = gx[i];
        float val = ex[i];
        if (msk && (x < lb || x > ub)) val += (x > 0.f) ? EPS_ : -EPS_;
        ss += val * val;
        h[i] = (_Float16)val;
    }
    *(half8*)(pf16 + (size_t)row * E_ + ln * 8) = h;
    ss = wave_sum(ss);
    if (ln == 0) inv_p[row] = 1.f / fmaxf(sqrtf(ss), 1e-8f);
}

// ---------------- K6: emb -> f16 (zero-padded) + 1/t_norm -------------------
__global__ void k_emb(const float* __restrict__ emb, _Float16* __restrict__ ef16,
                      float* __restrict__ inv_t) {
    const int row = blockIdx.x * 4 + (threadIdx.x >> 6);
    const int ln  = threadIdx.x & 63;
    half8 h;
    float ss = 0.f;
    if (row < V_) {
        const float* ep = emb + (size_t)row * E_ + ln * 8;
        float4 e0 = *(const float4*)ep, e1 = *(const float4*)(ep + 4);
        float ex[8] = {e0.x, e0.y, e0.z, e0.w, e1.x, e1.y, e1.z, e1.w};
#pragma unroll
        for (int i = 0; i < 8; ++i) { ss += ex[i] * ex[i]; h[i] = (_Float16)ex[i]; }
    } else {
#pragma unroll
        for (int i = 0; i < 8; ++i) h[i] = (_Float16)0.f;
    }
    *(half8*)(ef16 + (size_t)row * E_ + ln * 8) = h;
    ss = wave_sum(ss);
    if (ln == 0) inv_t[row] = (row < V_) ? 1.f / fmaxf(sqrtf(ss), 1e-8f) : 0.f;
}

// ---------------- K7: GEMM + normalize + store + argmax ---------------------
__device__ __forceinline__ void glds16(const _Float16* g, void* l) {
    __builtin_amdgcn_global_load_lds(
        (const __attribute__((address_space(1))) void*)g,
        (__attribute__((address_space(3))) void*)l, 16, 0, 0);
}

__global__ __launch_bounds__(256) void k_gemm(
    const _Float16* __restrict__ A,    // [M_][E_] perturbed f16
    const _Float16* __restrict__ Bm,   // [NPAD_][E_] emb f16
    const float* __restrict__ inv_p,   // [M_]
    const float* __restrict__ inv_t,   // [NPAD_]
    float* __restrict__ simout,        // [M_][V_]
    unsigned long long* __restrict__ keys) {
    __shared__ _Float16 As[2][128][32];
    __shared__ _Float16 Bs[2][128][32];
    const int tid = threadIdx.x;
    const int wv = tid >> 6, ln = tid & 63;

    // XCD-chunk swizzle (bijective: 6288 = 8*786), then M-tile fastest so 16
    // consecutive blocks on one XCD share a B-panel and keep A L2-resident.
    const int orig = blockIdx.x;
    const int wg = (orig & 7) * CPX_ + (orig >> 3);
    const int m0 = (wg & 15) * 128;
    const int n0 = (wg >> 4) * 128;

    const int wr = wv >> 1, wc = wv & 1;
    const int lr = ln & 15, lk = (ln >> 4) * 8;

    f32x4 acc[4][4];
#pragma unroll
    for (int i = 0; i < 4; ++i)
#pragma unroll
        for (int j = 0; j < 4; ++j) acc[i][j] = (f32x4){0.f, 0.f, 0.f, 0.f};

    // staging map: thread loads 16B; tile row = it*64 + wv*16 + (ln>>2), col = (ln&3)*8
    const int srow = wv * 16 + (ln >> 2);
    const int scol = (ln & 3) * 8;
    const _Float16* gA = A  + (size_t)(m0 + srow) * E_ + scol;
    const _Float16* gB = Bm + (size_t)(n0 + srow) * E_ + scol;

#define STAGE(buf, k0) do {                                         \
        char* lA_ = (char*)&As[buf][0][0] + wv * 1024;              \
        char* lB_ = (char*)&Bs[buf][0][0] + wv * 1024;              \
        glds16(gA + (k0),            lA_);                          \
        glds16(gA + 64 * E_ + (k0),  lA_ + 4096);                   \
        glds16(gB + (k0),            lB_);                          \
        glds16(gB + 64 * E_ + (k0),  lB_ + 4096);                   \
    } while (0)

#define COMPUTE(buf) do {                                           \
        half8 af[4], bf[4];                                         \
        _Pragma("unroll")                                           \
        for (int f = 0; f < 4; ++f) {                               \
            af[f] = *(const half8*)&As[buf][wr * 64 + f * 16 + lr][lk]; \
            bf[f] = *(const half8*)&Bs[buf][wc * 64 + f * 16 + lr][lk]; \
        }                                                           \
        _Pragma("unroll")                                           \
        for (int i = 0; i < 4; ++i)                                 \
            _Pragma("unroll")                                       \
            for (int j = 0; j < 4; ++j)                             \
                acc[i][j] = __builtin_amdgcn_mfma_f32_16x16x32_f16(af[i], bf[j], acc[i][j], 0, 0, 0); \
    } while (0)

    STAGE(0, 0);
    __syncthreads();                 // drains vmcnt(0) too
    int cur = 0;
#pragma unroll 2
    for (int t = 0; t < 15; ++t) {
        STAGE(cur ^ 1, (t + 1) * 32);   // prefetch next tile; hides under compute
        COMPUTE(cur);
        __syncthreads();                 // vmcnt(0) + barrier: next tile ready, cur free
        cur ^= 1;
    }
    COMPUTE(cur);                        // last tile, no prefetch
#undef STAGE
#undef COMPUTE

    // epilogue: C/D layout col = lane&15, row = (lane>>4)*4 + reg
    int vv[4];
    float itv[4];
#pragma unroll
    for (int fn = 0; fn < 4; ++fn) {
        vv[fn] = n0 + wc * 64 + fn * 16 + lr;
        itv[fn] = inv_t[vv[fn]];
    }
#pragma unroll
    for (int fm = 0; fm < 4; ++fm) {
#pragma unroll
        for (int j = 0; j < 4; ++j) {
            const int m = m0 + wr * 64 + fm * 16 + (ln >> 4) * 4 + j;
            const float ip = inv_p[m];
            float* orow = simout + (size_t)m * V_;
            unsigned long long best = 0ull;
#pragma unroll
            for (int fn = 0; fn < 4; ++fn) {
                const int v = vv[fn];
                if (v < V_) {
                    const float sv = acc[fm][fn][j] * ip * itv[fn];
                    orow[v] = sv;
                    unsigned u = __float_as_uint(sv);
                    u = (u & 0x80000000u) ? ~u : (u | 0x80000000u);
                    unsigned long long e = ((unsigned long long)u << 32) | (unsigned)(~v);
                    best = e > best ? e : best;
                }
            }
#pragma unroll
            for (int d = 1; d < 16; d <<= 1) {
                unsigned long long o = __shfl_xor(best, d);
                best = o > best ? o : best;
            }
            if (lr == 0) atomicMax(keys + m, best);
        }
    }
}

// ---------------- K8: decode argmax keys -> float indices -------------------
__global__ void k_idx(const unsigned long long* __restrict__ keys, float* __restrict__ out) {
    const int i = blockIdx.x * 256 + threadIdx.x;
    if (i < M_) {
        unsigned v = ~(unsigned)(keys[i] & 0xFFFFFFFFull);
        out[i] = (float)v;
    }
}

extern "C" void kernel_launch(void* const* d_in, const int* in_sizes, int n_in,
                              void* d_out, int out_size, void* d_ws, size_t ws_size,
                              hipStream_t stream) {
    const int*   utt  = (const int*)d_in[0];
    const float* emb  = (const float*)d_in[1];
    const float* grad = (const float*)d_in[2];

    char* ws = (char*)d_ws;
    _Float16* embF16  = (_Float16*)(ws);                    // 50304*512*2 = 51,511,296
    _Float16* pertF16 = (_Float16*)(ws + 51511296);         // 2048*512*2  =  2,097,152
    float* inv_t = (float*)(ws + 53608448);                 // 50304*4
    float* inv_p = (float*)(ws + 53809664);                 // 2048*4
    float* absg  = (float*)(ws + 53817856);                 // 2048*4
    int*   mask  = (int*)  (ws + 53826048);                 // 2048*4
    float* part  = (float*)(ws + 53834240);                 // 128*2*4
    float* stats = (float*)(ws + 53835264);                 // 2 floats
    unsigned long long* keys = (unsigned long long*)(ws + 53835520); // 2048*8

    float* outIdx = (float*)d_out;          // nn_idx as float32 [2048]
    float* simout = (float*)d_out + M_;     // sim [2048][50257]

    hipMemsetAsync(keys, 0, M_ * 8, stream);
    k_absgrad<<<M_ / 4, 256, 0, stream>>>(grad, absg);
    k_topk<<<B_, S_, 0, stream>>>(absg, mask);
    k_stats1<<<128, 256, 0, stream>>>(grad, mask, part);
    k_stats2<<<1, 64, 0, stream>>>(part, stats);
    k_pert<<<M_ / 4, 256, 0, stream>>>(grad, emb, utt, mask, stats, pertF16, inv_p);
    k_emb<<<NPAD_ / 4, 256, 0, stream>>>(emb, embF16, inv_t);
    k_gemm<<<NWG_, 256, 0, stream>>>(pertF16, embF16, inv_p, inv_t, simout, keys);
    k_idx<<<8, 256, 0, stream>>>(keys, outIdx);
}